// Round 10
// baseline (275.348 us; speedup 1.0000x reference)
//
#include <hip/hip_runtime.h>

#define B_ROWS 4096
#define N_COLS 8192
#define BLOCK  256
#define VPT    (N_COLS / 4 / BLOCK)   // float4 loads per thread per input = 8

// Native clang vector: __builtin_nontemporal_load rejects HIP_vector_type.
typedef float vfloat4 __attribute__((ext_vector_type(4)));

// Journal R1-R9:
//  - R2-R4: compiler clamps register-load MLP to ~2/wave (launch_bounds,
//    sched_barrier neutral). 2.7 TB/s effective.
//  - R5/R8: 16-deep global_load_lds DMA queues do NOT beat 2-deep register
//    loads -> service-rate wall, not latency.
//  - R7 WIN: non-temporal loads (no L3 allocation on miss) row 99 -> ~71 us.
//    Pre-NT wall was Infinity-Cache fill/eviction traffic.
//  - R9: single-stream phasing neutral -> post-NT read rate (~3.8 TB/s) is
//    structure-independent; bench floor dominated by overlapped harness
//    restore traffic (~1.2 GB/iter at ~6.9 TB/s).
//  - R10: R7 form + fused mean (atomicAdd per block, memsetAsync init) to
//    drop the second launch and the row_loss round-trip.
__global__ __launch_bounds__(BLOCK) void row_pearson_kernel(
    const float* __restrict__ preds,
    const float* __restrict__ labels,
    float* __restrict__ out)
{
    const int row = blockIdx.x;
    const int tid = threadIdx.x;

    const vfloat4* p4 = reinterpret_cast<const vfloat4*>(preds  + (size_t)row * N_COLS);
    const vfloat4* l4 = reinterpret_cast<const vfloat4*>(labels + (size_t)row * N_COLS);

    float sx = 0.f, sy = 0.f, sxy = 0.f, sxx = 0.f, syy = 0.f;

    #pragma unroll
    for (int i = 0; i < VPT; ++i) {
        const vfloat4 x = __builtin_nontemporal_load(p4 + tid + i * BLOCK);
        const vfloat4 y = __builtin_nontemporal_load(l4 + tid + i * BLOCK);
        sx  += x.x + x.y + x.z + x.w;
        sy  += y.x + y.y + y.z + y.w;
        sxy += x.x * y.x + x.y * y.y + x.z * y.z + x.w * y.w;
        sxx += x.x * x.x + x.y * x.y + x.z * x.z + x.w * x.w;
        syy += y.x * y.x + y.y * y.y + y.z * y.z + y.w * y.w;
    }

    // 64-lane wave reduction (wave = 64 on gfx950).
    #pragma unroll
    for (int off = 32; off > 0; off >>= 1) {
        sx  += __shfl_down(sx,  off);
        sy  += __shfl_down(sy,  off);
        sxy += __shfl_down(sxy, off);
        sxx += __shfl_down(sxx, off);
        syy += __shfl_down(syy, off);
    }

    __shared__ float smem[4][5];   // 4 waves per block
    const int wave = tid >> 6;
    const int lane = tid & 63;
    if (lane == 0) {
        smem[wave][0] = sx;  smem[wave][1] = sy;  smem[wave][2] = sxy;
        smem[wave][3] = sxx; smem[wave][4] = syy;
    }
    __syncthreads();

    if (tid == 0) {
        float tx = 0.f, ty = 0.f, txy = 0.f, txx = 0.f, tyy = 0.f;
        #pragma unroll
        for (int w = 0; w < BLOCK / 64; ++w) {
            tx  += smem[w][0]; ty  += smem[w][1]; txy += smem[w][2];
            txx += smem[w][3]; tyy += smem[w][4];
        }
        const float Nf  = (float)N_COLS;
        const float num = Nf * txy - tx * ty;
        const float den = sqrtf((Nf * txx - tx * tx) * (Nf * tyy - ty * ty));
        // Fused mean: one device-scope atomic per block (4096 total).
        atomicAdd(out, (1.0f - num / den) * (1.0f / (float)B_ROWS));
    }
}

extern "C" void kernel_launch(void* const* d_in, const int* in_sizes, int n_in,
                              void* d_out, int out_size, void* d_ws, size_t ws_size,
                              hipStream_t stream) {
    const float* preds  = (const float*)d_in[0];
    const float* labels = (const float*)d_in[1];
    float* out = (float*)d_out;

    // d_out is re-poisoned to 0xAA before every timed launch; zero it
    // on-stream (graph-capture-safe, same call the harness uses).
    hipMemsetAsync(out, 0, sizeof(float), stream);
    row_pearson_kernel<<<B_ROWS, BLOCK, 0, stream>>>(preds, labels, out);
}